// Round 6
// baseline (584.601 us; speedup 1.0000x reference)
//
#include <hip/hip_runtime.h>
#include <hip/hip_bf16.h>
#include <hip/hip_cooperative_groups.h>

namespace cg = cooperative_groups;

#define RS   100            // row stride (floats) of a 97x97 plane (padded for float4 alignment)
#define PLS  9700           // plane stride = 97 rows * RS
#define NP   9409           // 97*97 valid elements per plane

// ws layout (float offsets) — weights read directly from d_in (fp32)
#define OFF_R   0                          // 4*32 planes (pooled relations, padded/shifted)
#define OFF_A   (OFF_R  + 4*32*PLS)        // 4*16 planes (ft projection)
#define OFF_Bm  (OFF_A  + 4*16*PLS)        // 4*16 planes (rt projection)
#define OFF_F1  (OFF_Bm + 4*16*PLS)        // 4*16 planes (dp step-0 output)
#define OFF_F2  (OFF_F1 + 4*16*PLS)        // 4*16 planes (dp step-1 output)
#define OFF_T   (OFF_F2 + 4*16*PLS)        // 128 x 96 x 96 scratch for pool substage
// total ~4.9M floats (~19.6 MB) of the ~268 MB ws

#define MAXPLUS_TILES 1024

__device__ __forceinline__ float sigm(float x) { return 1.0f / (1.0f + __expf(-x)); }

// ==================== fused cooperative kernel ====================
// Stages: poolA -> poolB -> proj0 -> maxplus0 -> proj1 -> maxplus1 -> final
// LDS: 2 * 49 * 36 floats = 13.8 KB (maxplus chunks only). All stages grid-strided.
__global__ __launch_bounds__(256, 4) void fused_all(
        const float* __restrict__ a,
        const float* __restrict__ W0, const float* __restrict__ b0,
        const float* __restrict__ W1, const float* __restrict__ b1,
        const float* __restrict__ W2, const float* __restrict__ b2,
        float* __restrict__ ws, float* __restrict__ out) {
    cg::grid_group grid = cg::this_grid();
    __shared__ float As[49 * 36];
    __shared__ float Bs[49 * 36];
    const int tid = threadIdx.x;
    const int gsz = gridDim.x * 256;
    const int gtid = blockIdx.x * 256 + tid;

    float* R  = ws + OFF_R;
    float* A  = ws + OFF_A;
    float* Bm = ws + OFF_Bm;
    float* F1 = ws + OFF_F1;
    float* F2 = ws + OFF_F2;
    float* T  = ws + OFF_T;

    // ---- stage PA: masked load + reverse cummax over i (per column) -> T ----
    // item = (plane 0..127, column j 0..95); plane = b*32+ch; ch<16 max, >=16 min(-x)
    for (int p = gtid; p < 128 * 96; p += gsz) {
        const int plane = p / 96, j = p - (p / 96) * 96;
        const int b = plane >> 5, ch = plane & 31, d = ch & 15;
        const bool isMin = (ch >= 16);
        const float* ab = a + ((size_t)(b * 96) * 96 + j) * 16 + d;
        float* Tp = T + (size_t)plane * 9216 + j;
        float run = -1e30f;
        for (int i = 95; i >= 0; --i) {
            float v = ab[(size_t)i * 96 * 16];
            if (isMin) v = -v;
            run = fmaxf(run, (j >= i) ? v : -1e30f);
            Tp[i * 96] = run;
        }
    }
    grid.sync();

    // ---- stage PB: forward cummax over j (per row) -> padded R plane ----
    // item = (plane, row x 0..96). Writes ALL 97 y of the row (zeros where masked).
    for (int p = gtid; p < 128 * 97; p += gsz) {
        const int plane = p / 97, x = p - (p / 97) * 97;
        const int ch = plane & 31;
        const bool isMin = (ch >= 16);
        float* Rrow = R + (size_t)plane * PLS + x * RS;
        Rrow[0] = 0.f;
        if (x == 96) {
            for (int y = 1; y < 97; ++y) Rrow[y] = 0.f;
        } else {
            const float* Tp = T + (size_t)plane * 9216 + x * 96;
            float run = -1e30f;
            for (int j = 0; j < 96; ++j) {           // y = j+1
                run = fmaxf(run, Tp[j]);
                float v = 0.f;
                if (j >= x) v = isMin ? -run : run;  // mask i<=y-1
                Rrow[j + 1] = v;
            }
        }
    }
    grid.sync();

    // ---- stage proj0: A = r@Wf, Bm = r@Wr  (W0 64x16: rows 0..31 / 32..63) ----
    for (int p = gtid; p < 64 * NP; p += gsz) {
        const int bh = p / NP, idx = p - bh * NP;
        const int b = bh >> 4, h = bh & 15;
        const int x = idx / 97, y = idx - (idx / 97) * 97;
        const int off = x * RS + y;
        const float* Rb = R + (size_t)b * 32 * PLS + off;
        float accA = 0.f, accB = 0.f;
#pragma unroll
        for (int d = 0; d < 32; ++d) {
            float rv = Rb[(size_t)d * PLS];
            accA += rv * W0[d * 16 + h];
            accB += rv * W0[(32 + d) * 16 + h];
        }
        A[(size_t)bh * PLS + off]  = accA;
        Bm[(size_t)bh * PLS + off] = accB;
    }
    grid.sync();

    // ---- stage maxplus0 -> F1 (tiles grid-strided; K chunked 49+48) ----
    for (int t = blockIdx.x; t < MAXPLUS_TILES; t += gridDim.x) {
        const int bh = t >> 4, tt = t & 15;
        const int h = bh & 15;
        const int i0 = (tt & 3) * 32, j0 = (tt >> 2) * 32;
        const float* Ab = A  + (size_t)bh * PLS;
        const float* Bb = Bm + (size_t)bh * PLS;
        const int ty = tid >> 4, tx = tid & 15;
        float a00 = -1e30f, a01 = -1e30f, a10 = -1e30f, a11 = -1e30f;
        int kbase = 0;
#pragma unroll
        for (int chunk = 0; chunk < 2; ++chunk) {
            const int CH = chunk == 0 ? 49 : 48;
            __syncthreads();                          // protect LDS from previous use
            for (int idx = tid; idx < CH * 32; idx += 256) {
                int r = idx / CH, kk = idx - r * CH;  // consecutive idx -> consecutive kk (coalesced)
                int ii = i0 + r;
                As[kk * 36 + r] = (ii < 97) ? Ab[ii * RS + kbase + kk] : -1e30f;
            }
            for (int idx = tid; idx < CH * 32; idx += 256) {
                int kk = idx >> 5, c = idx & 31;      // consecutive idx -> consecutive jj (coalesced)
                int jj = j0 + c;
                Bs[kk * 36 + c] = (jj < 97) ? Bb[(kbase + kk) * RS + jj] : -1e30f;
            }
            __syncthreads();
            for (int kk = 0; kk < CH; ++kk) {
                const float2 a2 = *reinterpret_cast<const float2*>(&As[kk * 36 + ty * 2]);
                const float2 b2v = *reinterpret_cast<const float2*>(&Bs[kk * 36 + tx * 2]);
                a00 = fmaxf(a00, a2.x + b2v.x);
                a01 = fmaxf(a01, a2.x + b2v.y);
                a10 = fmaxf(a10, a2.y + b2v.x);
                a11 = fmaxf(a11, a2.y + b2v.y);
            }
            kbase += CH;
        }
        const float bb = b0[h];
        float* Fb = F1 + (size_t)bh * PLS;
        const int col0 = j0 + tx * 2, row0 = i0 + ty * 2;
        float v[2][2] = {{a00, a01}, {a10, a11}};
#pragma unroll
        for (int r = 0; r < 2; ++r) {
            const int row = row0 + r;
            if (row > 96) continue;
            if (col0 + 1 <= 96) {
                float2 o; o.x = sigm(v[r][0] + bb); o.y = sigm(v[r][1] + bb);
                *reinterpret_cast<float2*>(&Fb[row * RS + col0]) = o;
            } else if (col0 <= 96) {
                Fb[row * RS + col0] = sigm(v[r][0] + bb);
            }
        }
    }
    grid.sync();

    // ---- stage proj1: A = [f1,r]@Wf, Bm = r@Wr  (W1 80x16: 0..15 f1, 16..47 r, 48..79 r) ----
    for (int p = gtid; p < 64 * NP; p += gsz) {
        const int bh = p / NP, idx = p - bh * NP;
        const int b = bh >> 4, h = bh & 15;
        const int x = idx / 97, y = idx - (idx / 97) * 97;
        const int off = x * RS + y;
        const float* Rb = R  + (size_t)b * 32 * PLS + off;
        const float* Fb = F1 + (size_t)b * 16 * PLS + off;
        float accA = 0.f, accB = 0.f;
#pragma unroll
        for (int c = 0; c < 16; ++c) accA += Fb[(size_t)c * PLS] * W1[c * 16 + h];
#pragma unroll
        for (int d = 0; d < 32; ++d) {
            float rv = Rb[(size_t)d * PLS];
            accA += rv * W1[(16 + d) * 16 + h];
            accB += rv * W1[(48 + d) * 16 + h];
        }
        A[(size_t)bh * PLS + off]  = accA;
        Bm[(size_t)bh * PLS + off] = accB;
    }
    grid.sync();

    // ---- stage maxplus1 -> F2 ----
    for (int t = blockIdx.x; t < MAXPLUS_TILES; t += gridDim.x) {
        const int bh = t >> 4, tt = t & 15;
        const int h = bh & 15;
        const int i0 = (tt & 3) * 32, j0 = (tt >> 2) * 32;
        const float* Ab = A  + (size_t)bh * PLS;
        const float* Bb = Bm + (size_t)bh * PLS;
        const int ty = tid >> 4, tx = tid & 15;
        float a00 = -1e30f, a01 = -1e30f, a10 = -1e30f, a11 = -1e30f;
        int kbase = 0;
#pragma unroll
        for (int chunk = 0; chunk < 2; ++chunk) {
            const int CH = chunk == 0 ? 49 : 48;
            __syncthreads();
            for (int idx = tid; idx < CH * 32; idx += 256) {
                int r = idx / CH, kk = idx - r * CH;
                int ii = i0 + r;
                As[kk * 36 + r] = (ii < 97) ? Ab[ii * RS + kbase + kk] : -1e30f;
            }
            for (int idx = tid; idx < CH * 32; idx += 256) {
                int kk = idx >> 5, c = idx & 31;
                int jj = j0 + c;
                Bs[kk * 36 + c] = (jj < 97) ? Bb[(kbase + kk) * RS + jj] : -1e30f;
            }
            __syncthreads();
            for (int kk = 0; kk < CH; ++kk) {
                const float2 a2 = *reinterpret_cast<const float2*>(&As[kk * 36 + ty * 2]);
                const float2 b2v = *reinterpret_cast<const float2*>(&Bs[kk * 36 + tx * 2]);
                a00 = fmaxf(a00, a2.x + b2v.x);
                a01 = fmaxf(a01, a2.x + b2v.y);
                a10 = fmaxf(a10, a2.y + b2v.x);
                a11 = fmaxf(a11, a2.y + b2v.y);
            }
            kbase += CH;
        }
        const float bb = b1[h];
        float* Fb = F2 + (size_t)bh * PLS;
        const int col0 = j0 + tx * 2, row0 = i0 + ty * 2;
        float v[2][2] = {{a00, a01}, {a10, a11}};
#pragma unroll
        for (int r = 0; r < 2; ++r) {
            const int row = row0 + r;
            if (row > 96) continue;
            if (col0 + 1 <= 96) {
                float2 o; o.x = sigm(v[r][0] + bb); o.y = sigm(v[r][1] + bb);
                *reinterpret_cast<float2*>(&Fb[row * RS + col0]) = o;
            } else if (col0 <= 96) {
                Fb[row * RS + col0] = sigm(v[r][0] + bb);
            }
        }
    }
    grid.sync();

    // ---- stage final: out = sigmoid([f2,r] @ W2 + b2), cropped [:, :-1, 1:] ----
    for (int p = gtid; p < 4 * 96 * 96; p += gsz) {
        const int oj = p % 96;
        const int t1 = p / 96;
        const int i  = t1 % 96;
        const int b  = t1 / 96;
        const int off = i * RS + (oj + 1);
        const float* Fb = F2 + (size_t)b * 16 * PLS + off;
        const float* Rb = R  + (size_t)b * 32 * PLS + off;
        float acc[16];
#pragma unroll
        for (int o = 0; o < 16; ++o) acc[o] = b2[o];
#pragma unroll
        for (int c = 0; c < 16; ++c) {
            const float fv = Fb[(size_t)c * PLS];
#pragma unroll
            for (int o = 0; o < 16; ++o) acc[o] += fv * W2[c * 16 + o];
        }
#pragma unroll
        for (int d = 0; d < 32; ++d) {
            const float rv = Rb[(size_t)d * PLS];
#pragma unroll
            for (int o = 0; o < 16; ++o) acc[o] += rv * W2[(16 + d) * 16 + o];
        }
        float4* dst = reinterpret_cast<float4*>(out + (size_t)p * 16);
#pragma unroll
        for (int q = 0; q < 4; ++q) {
            float4 v;
            v.x = sigm(acc[q * 4 + 0]);
            v.y = sigm(acc[q * 4 + 1]);
            v.z = sigm(acc[q * 4 + 2]);
            v.w = sigm(acc[q * 4 + 3]);
            dst[q] = v;
        }
    }
}

// ==================== fallback path (R4 pipeline, known-good) ====================

__global__ __launch_bounds__(128) void pool_kernel(const float* __restrict__ a, float* __restrict__ R) {
    __shared__ float s[96][97];
    const int tid = threadIdx.x;
    const int b  = blockIdx.x >> 5;
    const int ch = blockIdx.x & 31;
    const int d  = ch & 15;
    const bool isMin = (ch >= 16);
    for (int idx = tid; idx < 96 * 96; idx += 128) {
        int i = idx / 96, j = idx - i * 96;
        float v = a[((size_t)(b * 96 + i) * 96 + j) * 16 + d];
        if (isMin) v = -v;
        s[i][j] = (j >= i) ? v : -1e30f;
    }
    __syncthreads();
    if (tid < 96) {
        int j = tid; float run = -1e30f;
        for (int i = 95; i >= 0; --i) { run = fmaxf(run, s[i][j]); s[i][j] = run; }
    }
    __syncthreads();
    if (tid < 96) {
        int i = tid; float run = -1e30f;
        for (int j = 0; j < 96; ++j) { run = fmaxf(run, s[i][j]); s[i][j] = run; }
    }
    __syncthreads();
    float* Rp = R + (size_t)blockIdx.x * PLS;
    for (int idx = tid; idx < 97 * 97; idx += 128) {
        int x = idx / 97, y = idx - x * 97;
        float v = 0.f;
        if (x <= 95 && y >= 1 && x <= y - 1) { v = s[x][y - 1]; if (isMin) v = -v; }
        Rp[x * RS + y] = v;
    }
}

__global__ __launch_bounds__(256) void proj0_kernel(const float* __restrict__ R, const float* __restrict__ W,
                                                    float* __restrict__ A, float* __restrict__ B) {
    const int bh = blockIdx.y, b = bh >> 4, h = bh & 15;
    const int p = blockIdx.x * 256 + threadIdx.x;
    if (p >= NP) return;
    const int x = p / 97, y = p - x * 97;
    const int off = x * RS + y;
    const float* Rb = R + (size_t)b * 32 * PLS + off;
    float accA = 0.f, accB = 0.f;
#pragma unroll
    for (int d = 0; d < 32; ++d) {
        float rv = Rb[(size_t)d * PLS];
        accA += rv * W[d * 16 + h];
        accB += rv * W[(32 + d) * 16 + h];
    }
    A[(size_t)bh * PLS + off] = accA;
    B[(size_t)bh * PLS + off] = accB;
}

__global__ __launch_bounds__(256) void proj1_kernel(const float* __restrict__ R, const float* __restrict__ F1,
                                                    const float* __restrict__ W,
                                                    float* __restrict__ A, float* __restrict__ B) {
    const int bh = blockIdx.y, b = bh >> 4, h = bh & 15;
    const int p = blockIdx.x * 256 + threadIdx.x;
    if (p >= NP) return;
    const int x = p / 97, y = p - x * 97;
    const int off = x * RS + y;
    const float* Rb = R  + (size_t)b * 32 * PLS + off;
    const float* Fb = F1 + (size_t)b * 16 * PLS + off;
    float accA = 0.f, accB = 0.f;
#pragma unroll
    for (int c = 0; c < 16; ++c) accA += Fb[(size_t)c * PLS] * W[c * 16 + h];
#pragma unroll
    for (int d = 0; d < 32; ++d) {
        float rv = Rb[(size_t)d * PLS];
        accA += rv * W[(16 + d) * 16 + h];
        accB += rv * W[(48 + d) * 16 + h];
    }
    A[(size_t)bh * PLS + off] = accA;
    B[(size_t)bh * PLS + off] = accB;
}

__global__ __launch_bounds__(256) void maxplus_kernel(const float* __restrict__ A, const float* __restrict__ Bm,
                                                      const float* __restrict__ bias, float* __restrict__ F) {
    __shared__ alignas(16) float As[97][36];
    __shared__ alignas(16) float Bs[97][36];
    const int tid = threadIdx.x;
    const int bh = blockIdx.y;
    const int h  = bh & 15;
    const int i0 = (blockIdx.x & 3) * 32;
    const int j0 = (blockIdx.x >> 2) * 32;
    const float* Ab = A  + (size_t)bh * PLS;
    const float* Bb = Bm + (size_t)bh * PLS;
    for (int idx = tid; idx < 32 * 97; idx += 256) {
        int r = idx / 97, k = idx - r * 97;
        int ii = i0 + r;
        As[k][r] = (ii < 97) ? Ab[ii * RS + k] : -1e30f;
    }
    for (int idx = tid; idx < 97 * 32; idx += 256) {
        int k = idx >> 5, c = idx & 31;
        int jj = j0 + c;
        Bs[k][c] = (jj < 97) ? Bb[k * RS + jj] : -1e30f;
    }
    __syncthreads();
    const int ty = tid >> 4, tx = tid & 15;
    float a00 = -1e30f, a01 = -1e30f, a10 = -1e30f, a11 = -1e30f;
#pragma unroll 4
    for (int k = 0; k < 97; ++k) {
        const float2 a2 = *reinterpret_cast<const float2*>(&As[k][ty * 2]);
        const float2 b2 = *reinterpret_cast<const float2*>(&Bs[k][tx * 2]);
        a00 = fmaxf(a00, a2.x + b2.x);
        a01 = fmaxf(a01, a2.x + b2.y);
        a10 = fmaxf(a10, a2.y + b2.x);
        a11 = fmaxf(a11, a2.y + b2.y);
    }
    const float bb = bias[h];
    float* Fb = F + (size_t)bh * PLS;
    const int col0 = j0 + tx * 2;
    const int row0 = i0 + ty * 2;
    float v[2][2] = {{a00, a01}, {a10, a11}};
#pragma unroll
    for (int r = 0; r < 2; ++r) {
        const int row = row0 + r;
        if (row > 96) continue;
        if (col0 + 1 <= 96) {
            float2 o;
            o.x = sigm(v[r][0] + bb);
            o.y = sigm(v[r][1] + bb);
            *reinterpret_cast<float2*>(&Fb[row * RS + col0]) = o;
        } else if (col0 <= 96) {
            Fb[row * RS + col0] = sigm(v[r][0] + bb);
        }
    }
}

__global__ __launch_bounds__(256) void final_kernel(const float* __restrict__ R, const float* __restrict__ F2,
                                                    const float* __restrict__ W, const float* __restrict__ bias,
                                                    float* __restrict__ out) {
    const int p = blockIdx.x * 256 + threadIdx.x;
    if (p >= 4 * 96 * 96) return;
    const int oj = p % 96;
    const int t1 = p / 96;
    const int i  = t1 % 96;
    const int b  = t1 / 96;
    const int off = i * RS + (oj + 1);
    const float* Fb = F2 + (size_t)b * 16 * PLS + off;
    const float* Rb = R  + (size_t)b * 32 * PLS + off;
    float acc[16];
#pragma unroll
    for (int o = 0; o < 16; ++o) acc[o] = bias[o];
#pragma unroll
    for (int c = 0; c < 16; ++c) {
        const float fv = Fb[(size_t)c * PLS];
#pragma unroll
        for (int o = 0; o < 16; ++o) acc[o] += fv * W[c * 16 + o];
    }
#pragma unroll
    for (int d = 0; d < 32; ++d) {
        const float rv = Rb[(size_t)d * PLS];
#pragma unroll
        for (int o = 0; o < 16; ++o) acc[o] += rv * W[(16 + d) * 16 + o];
    }
    float4* dst = reinterpret_cast<float4*>(out + (size_t)p * 16);
#pragma unroll
    for (int q = 0; q < 4; ++q) {
        float4 v;
        v.x = sigm(acc[q * 4 + 0]);
        v.y = sigm(acc[q * 4 + 1]);
        v.z = sigm(acc[q * 4 + 2]);
        v.w = sigm(acc[q * 4 + 3]);
        dst[q] = v;
    }
}

static void launch_fallback(const float* a, const float* W0, const float* b0,
                            const float* W1, const float* b1,
                            const float* W2, const float* b2,
                            float* ws, float* out, hipStream_t stream) {
    hipLaunchKernelGGL(pool_kernel, dim3(128), dim3(128), 0, stream, a, ws + OFF_R);
    hipLaunchKernelGGL(proj0_kernel, dim3(37, 64), dim3(256), 0, stream,
                       ws + OFF_R, W0, ws + OFF_A, ws + OFF_Bm);
    hipLaunchKernelGGL(maxplus_kernel, dim3(16, 64), dim3(256), 0, stream,
                       ws + OFF_A, ws + OFF_Bm, b0, ws + OFF_F1);
    hipLaunchKernelGGL(proj1_kernel, dim3(37, 64), dim3(256), 0, stream,
                       ws + OFF_R, ws + OFF_F1, W1, ws + OFF_A, ws + OFF_Bm);
    hipLaunchKernelGGL(maxplus_kernel, dim3(16, 64), dim3(256), 0, stream,
                       ws + OFF_A, ws + OFF_Bm, b1, ws + OFF_F2);
    hipLaunchKernelGGL(final_kernel, dim3(144), dim3(256), 0, stream,
                       ws + OFF_R, ws + OFF_F2, W2, b2, out);
}

extern "C" void kernel_launch(void* const* d_in, const int* in_sizes, int n_in,
                              void* d_out, int out_size, void* d_ws, size_t ws_size,
                              hipStream_t stream) {
    const float* a  = (const float*)d_in[0];
    const float* W0 = (const float*)d_in[1];
    const float* b0 = (const float*)d_in[2];
    const float* W1 = (const float*)d_in[3];
    const float* b1 = (const float*)d_in[4];
    const float* W2 = (const float*)d_in[5];
    const float* b2 = (const float*)d_in[6];
    float* ws  = (float*)d_ws;
    float* out = (float*)d_out;

    // Size the cooperative grid from the runtime's own occupancy model
    // (host-side query: capture-safe, deterministic across calls).
    int perCU = 0, numCU = 0;
    hipError_t e1 = hipOccupancyMaxActiveBlocksPerMultiprocessor(&perCU, (const void*)fused_all, 256, 0);
    hipError_t e2 = hipDeviceGetAttribute(&numCU, hipDeviceAttributeMultiprocessorCount, 0);

    bool coop_ok = (e1 == hipSuccess && e2 == hipSuccess && perCU >= 1 && numCU >= 1);
    if (coop_ok) {
        long long maxBlk = (long long)perCU * numCU;
        int gridBlocks = (int)(maxBlk < MAXPLUS_TILES ? maxBlk : MAXPLUS_TILES);
        void* args[] = {(void*)&a, (void*)&W0, (void*)&b0, (void*)&W1, (void*)&b1,
                        (void*)&W2, (void*)&b2, (void*)&ws, (void*)&out};
        hipError_t el = hipLaunchCooperativeKernel((const void*)fused_all, dim3(gridBlocks),
                                                   dim3(256), args, 0, stream);
        if (el == hipSuccess) return;
    }
    launch_fallback(a, W0, b0, W1, b1, W2, b2, ws, out, stream);
}

// Round 7
// 151.869 us; speedup vs baseline: 3.8494x; 3.8494x over previous
//
#include <hip/hip_runtime.h>
#include <hip/hip_bf16.h>

#define RS   100            // row stride (floats) of a 97x97 plane (padded for float4 alignment)
#define PLS  9700           // plane stride = 97 rows * RS
#define NP   9409           // 97*97 valid elements per plane
#define LSTR 34             // maxplus LDS row stride: bank=(2k+r)%32 -> worst 2-way (free); 8B-aligned

// ws layout (float offsets) — weights read directly from d_in (fp32)
#define OFF_R   0                          // 4*32 planes (pooled relations, padded/shifted)
#define OFF_A   (OFF_R  + 4*32*PLS)        // 4*16 planes (ft projection)
#define OFF_Bm  (OFF_A  + 4*16*PLS)        // 4*16 planes (rt projection)
#define OFF_F1  (OFF_Bm + 4*16*PLS)        // 4*16 planes (dp step-0 output)
#define OFF_F2  (OFF_F1 + 4*16*PLS)        // 4*16 planes (dp step-1 output)
// total = 384 planes * 9700 * 4 B = 14.9 MB of ws

__device__ __forceinline__ float sigm(float x) { return 1.0f / (1.0f + __expf(-x)); }

// ---------------- interval pooling (max & min) + pad -> R planes ----------------
// One block per (b, ch); ch<16: max over channel ch, ch>=16: min over channel ch-16
// (min computed as -cummax(-x)). Output R[(b*32+ch)][x][y] = padded r, zeros outside.
__global__ __launch_bounds__(256) void pool_kernel(const float* __restrict__ a, float* __restrict__ R) {
    __shared__ float s[96][97];   // +1 pad: scans hit distinct banks both directions
    const int tid = threadIdx.x;
    const int b  = blockIdx.x >> 5;
    const int ch = blockIdx.x & 31;
    const int d  = ch & 15;
    const bool isMin = (ch >= 16);

    for (int idx = tid; idx < 96 * 96; idx += 256) {
        int i = idx / 96, j = idx - i * 96;
        float v = a[((size_t)(b * 96 + i) * 96 + j) * 16 + d];
        if (isMin) v = -v;
        s[i][j] = (j >= i) ? v : -1e30f;
    }
    __syncthreads();
    if (tid < 96) {              // reverse cummax over i (thread = column j)
        int j = tid; float run = -1e30f;
#pragma unroll 4
        for (int i = 95; i >= 0; --i) { run = fmaxf(run, s[i][j]); s[i][j] = run; }
    }
    __syncthreads();
    if (tid < 96) {              // forward cummax over j (thread = row i)
        int i = tid; float run = -1e30f;
#pragma unroll 4
        for (int j = 0; j < 96; ++j) { run = fmaxf(run, s[i][j]); s[i][j] = run; }
    }
    __syncthreads();
    // write padded plane: r[x][y] = pool[x][y-1] if (x<=95 && y>=1 && x<=y-1) else 0
    float* Rp = R + (size_t)blockIdx.x * PLS;
    for (int idx = tid; idx < 97 * 97; idx += 256) {
        int x = idx / 97, y = idx - x * 97;
        float v = 0.f;
        if (x <= 95 && y >= 1 && x <= y - 1) { v = s[x][y - 1]; if (isMin) v = -v; }
        Rp[x * RS + y] = v;
    }
}

// ---------------- projection step 0: A = r@Wf, B = r@Wr ----------------
// W = W0 (64x16): Wf = rows 0..31, Wr = rows 32..63. 2368-block parallelism.
__global__ __launch_bounds__(256) void proj0_kernel(const float* __restrict__ R, const float* __restrict__ W,
                                                    float* __restrict__ A, float* __restrict__ B) {
    const int bh = blockIdx.y, b = bh >> 4, h = bh & 15;
    const int p = blockIdx.x * 256 + threadIdx.x;
    if (p >= NP) return;
    const int x = p / 97, y = p - x * 97;
    const int off = x * RS + y;
    const float* Rb = R + (size_t)b * 32 * PLS + off;
    float accA = 0.f, accB = 0.f;
#pragma unroll
    for (int d = 0; d < 32; ++d) {
        float rv = Rb[(size_t)d * PLS];
        accA += rv * W[d * 16 + h];
        accB += rv * W[(32 + d) * 16 + h];
    }
    A[(size_t)bh * PLS + off] = accA;
    B[(size_t)bh * PLS + off] = accB;
}

// ---------------- projection step 1: A = [f1,r]@Wf, B = r@Wr ----------------
// W = W1 (80x16): rows 0..15 -> f1, 16..47 -> r (Wf), 48..79 -> r (Wr)
__global__ __launch_bounds__(256) void proj1_kernel(const float* __restrict__ R, const float* __restrict__ F1,
                                                    const float* __restrict__ W,
                                                    float* __restrict__ A, float* __restrict__ B) {
    const int bh = blockIdx.y, b = bh >> 4, h = bh & 15;
    const int p = blockIdx.x * 256 + threadIdx.x;
    if (p >= NP) return;
    const int x = p / 97, y = p - x * 97;
    const int off = x * RS + y;
    const float* Rb = R  + (size_t)b * 32 * PLS + off;
    const float* Fb = F1 + (size_t)b * 16 * PLS + off;
    float accA = 0.f, accB = 0.f;
#pragma unroll
    for (int c = 0; c < 16; ++c) accA += Fb[(size_t)c * PLS] * W[c * 16 + h];
#pragma unroll
    for (int d = 0; d < 32; ++d) {
        float rv = Rb[(size_t)d * PLS];
        accA += rv * W[(16 + d) * 16 + h];
        accB += rv * W[(48 + d) * 16 + h];
    }
    A[(size_t)bh * PLS + off] = accA;
    B[(size_t)bh * PLS + off] = accB;
}

// ---------------- max-plus "GEMM": F[i][j] = sigmoid(bias + max_k A[i][k]+B[k][j]) ----------------
// sigmoid monotonic => max_k sigmoid(.) = sigmoid(max_k .).
// 32x32 tiles: grid (16 tiles, 64 planes) = 1024 blocks (4+ blocks/CU).
// block 256 = 16x16 threads, 2x2 results each. LDS stride 34: staging writes 2-way max (free).
__global__ __launch_bounds__(256) void maxplus_kernel(const float* __restrict__ A, const float* __restrict__ Bm,
                                                      const float* __restrict__ bias, float* __restrict__ F) {
    __shared__ alignas(16) float As[97 * LSTR];  // As[k][i-local] (transposed)
    __shared__ alignas(16) float Bs[97 * LSTR];  // Bs[k][j-local]
    const int tid = threadIdx.x;
    const int bh = blockIdx.y;
    const int h  = bh & 15;
    const int i0 = (blockIdx.x & 3) * 32;
    const int j0 = (blockIdx.x >> 2) * 32;
    const float* Ab = A  + (size_t)bh * PLS;
    const float* Bb = Bm + (size_t)bh * PLS;

    for (int idx = tid; idx < 32 * 97; idx += 256) {      // A panel, transposed into LDS
        int r = idx / 97, k = idx - r * 97;               // consecutive tid -> consecutive k (coalesced)
        int ii = i0 + r;
        As[k * LSTR + r] = (ii < 97) ? Ab[ii * RS + k] : -1e30f;
    }
    for (int idx = tid; idx < 97 * 32; idx += 256) {      // B panel, direct
        int k = idx >> 5, c = idx & 31;                   // consecutive tid -> consecutive jj (coalesced)
        int jj = j0 + c;
        Bs[k * LSTR + c] = (jj < 97) ? Bb[k * RS + jj] : -1e30f;
    }
    __syncthreads();

    const int ty = tid >> 4, tx = tid & 15;
    float a00 = -1e30f, a01 = -1e30f, a10 = -1e30f, a11 = -1e30f;

#pragma unroll 4
    for (int k = 0; k < 97; ++k) {
        const float2 a2 = *reinterpret_cast<const float2*>(&As[k * LSTR + ty * 2]);  // broadcast in ty-group
        const float2 b2 = *reinterpret_cast<const float2*>(&Bs[k * LSTR + tx * 2]);  // spans all banks
        a00 = fmaxf(a00, a2.x + b2.x);
        a01 = fmaxf(a01, a2.x + b2.y);
        a10 = fmaxf(a10, a2.y + b2.x);
        a11 = fmaxf(a11, a2.y + b2.y);
    }

    const float bb = bias[h];
    float* Fb = F + (size_t)bh * PLS;
    const int col0 = j0 + tx * 2;
    const int row0 = i0 + ty * 2;
    float v[2][2] = {{a00, a01}, {a10, a11}};
#pragma unroll
    for (int r = 0; r < 2; ++r) {
        const int row = row0 + r;
        if (row > 96) continue;
        if (col0 + 1 <= 96) {
            float2 o;
            o.x = sigm(v[r][0] + bb);
            o.y = sigm(v[r][1] + bb);
            *reinterpret_cast<float2*>(&Fb[row * RS + col0]) = o;
        } else if (col0 <= 96) {
            Fb[row * RS + col0] = sigm(v[r][0] + bb);
        }
    }
}

// ---------------- final: out = sigmoid([f2,r] @ W2 + b2), cropped [:, :-1, 1:] ----------------
__global__ __launch_bounds__(256) void final_kernel(const float* __restrict__ R, const float* __restrict__ F2,
                                                    const float* __restrict__ W, const float* __restrict__ bias,
                                                    float* __restrict__ out) {
    const int p = blockIdx.x * 256 + threadIdx.x;
    if (p >= 4 * 96 * 96) return;
    const int oj = p % 96;
    const int t1 = p / 96;
    const int i  = t1 % 96;
    const int b  = t1 / 96;
    const int off = i * RS + (oj + 1);   // j = oj+1 (crop)
    const float* Fb = F2 + (size_t)b * 16 * PLS + off;
    const float* Rb = R  + (size_t)b * 32 * PLS + off;
    float acc[16];
#pragma unroll
    for (int o = 0; o < 16; ++o) acc[o] = bias[o];
#pragma unroll
    for (int c = 0; c < 16; ++c) {
        const float fv = Fb[(size_t)c * PLS];
#pragma unroll
        for (int o = 0; o < 16; ++o) acc[o] += fv * W[c * 16 + o];
    }
#pragma unroll
    for (int d = 0; d < 32; ++d) {
        const float rv = Rb[(size_t)d * PLS];
#pragma unroll
        for (int o = 0; o < 16; ++o) acc[o] += rv * W[(16 + d) * 16 + o];
    }
    float4* dst = reinterpret_cast<float4*>(out + (size_t)p * 16);
#pragma unroll
    for (int q = 0; q < 4; ++q) {
        float4 v;
        v.x = sigm(acc[q * 4 + 0]);
        v.y = sigm(acc[q * 4 + 1]);
        v.z = sigm(acc[q * 4 + 2]);
        v.w = sigm(acc[q * 4 + 3]);
        dst[q] = v;
    }
}

extern "C" void kernel_launch(void* const* d_in, const int* in_sizes, int n_in,
                              void* d_out, int out_size, void* d_ws, size_t ws_size,
                              hipStream_t stream) {
    const float* a  = (const float*)d_in[0];
    const float* W0 = (const float*)d_in[1];
    const float* b0 = (const float*)d_in[2];
    const float* W1 = (const float*)d_in[3];
    const float* b1 = (const float*)d_in[4];
    const float* W2 = (const float*)d_in[5];
    const float* b2 = (const float*)d_in[6];
    float* ws = (float*)d_ws;
    float* out = (float*)d_out;

    hipLaunchKernelGGL(pool_kernel, dim3(128), dim3(256), 0, stream, a, ws + OFF_R);
    hipLaunchKernelGGL(proj0_kernel, dim3(37, 64), dim3(256), 0, stream,
                       ws + OFF_R, W0, ws + OFF_A, ws + OFF_Bm);
    hipLaunchKernelGGL(maxplus_kernel, dim3(16, 64), dim3(256), 0, stream,
                       ws + OFF_A, ws + OFF_Bm, b0, ws + OFF_F1);
    hipLaunchKernelGGL(proj1_kernel, dim3(37, 64), dim3(256), 0, stream,
                       ws + OFF_R, ws + OFF_F1, W1, ws + OFF_A, ws + OFF_Bm);
    hipLaunchKernelGGL(maxplus_kernel, dim3(16, 64), dim3(256), 0, stream,
                       ws + OFF_A, ws + OFF_Bm, b1, ws + OFF_F2);
    hipLaunchKernelGGL(final_kernel, dim3(144), dim3(256), 0, stream,
                       ws + OFF_R, ws + OFF_F2, W2, b2, out);
}